// Round 8
// baseline (180.208 us; speedup 1.0000x reference)
//
#include <hip/hip_runtime.h>
#include <hip/hip_cooperative_groups.h>
#include <math.h>

namespace cg = cooperative_groups;

#define NF 1024
#define DIM 256
#define BATCH 2048
#define K 512            // interleaved (x^2, x) -> 2*DIM
#define BM 64
#define BN 64
#define NCHUNK (NF / BN) // 16
#define GRID 512

// ws layout (16B aligned):
//   [0, 2MB)    : Ab bf16[BATCH][K]  rows: (x^2, x) interleaved per dim
//   [2MB, 3MB)  : Bb bf16[NF][K]     rows: (s2, -2*s2*mu) interleaved per dim
//   [3MB, +4KB) : c  float[NF]
//   then        : rowPartial float[NCHUNK][BATCH]
#define WS_A_BYTES (BATCH * K * 2)
#define WS_B_OFF   WS_A_BYTES
#define WS_C_OFF   (WS_A_BYTES + NF * K * 2)
#define WS_RP_OFF  (WS_C_OFF + NF * 4)

typedef __attribute__((ext_vector_type(8))) short short8;   // 8 bf16
typedef __attribute__((ext_vector_type(4))) float f32x4;    // MFMA acc

__device__ __forceinline__ unsigned short f2bf(float f) {
    unsigned u = __float_as_uint(f);
    u += 0x7fffu + ((u >> 16) & 1u);       // RNE
    return (unsigned short)(u >> 16);
}

__device__ __forceinline__ void gl_lds16(const ushort* g, ushort* l) {
    __builtin_amdgcn_global_load_lds(
        (const __attribute__((address_space(1))) void*)g,
        (__attribute__((address_space(3))) void*)l, 16, 0, 0);
}

// ---------------------------------------------------------------------------
// One cooperative kernel, 512 blocks x 256 thr (2 blocks/CU co-resident).
// Phase 0: prep Ab/Bb/c (block-distributed).  grid.sync()
// Phase 1: 64x64 bf16 MFMA GEMM tile (r5 body); p kept in REGISTERS,
//          only 128KB rowPartial hits memory.      grid.sync()
// Phase 2: block-local 1/rowsum from rowPartial, scale regs, single out write.
__global__ __launch_bounds__(256, 2) void k_fused(const float* __restrict__ x,
                                                  const float* __restrict__ mu,
                                                  const float* __restrict__ sigma,
                                                  const float* __restrict__ temp,
                                                  float* __restrict__ out,
                                                  ushort* __restrict__ Ab,
                                                  ushort* __restrict__ Bb,
                                                  float* __restrict__ c,
                                                  float* __restrict__ rowPartial) {
    cg::grid_group grid = cg::this_grid();
    const int t = threadIdx.x;
    const int bid = blockIdx.x;          // 0..511

    __shared__ __align__(16) ushort Alds[BM * K];   // 64 KB
    __shared__ float sums[4][32];
    __shared__ float invRow[BM];
    __shared__ float red[4];

    unsigned int* Ab32 = (unsigned int*)Ab;
    unsigned int* Bb32 = (unsigned int*)Bb;

    // ---- phase 0: prep. 2 formulas + 4 x-rows per block. ----
    {
        const int lane = t & 63, wv = t >> 6;
        #pragma unroll
        for (int ff = 0; ff < 2; ++ff) {
            const int f = bid * 2 + ff;
            const float m = mu[f * DIM + t];
            const float s = sigma[f * DIM + t];
            const float s2 = s * s;
            Bb32[f * DIM + t] =
                (unsigned)f2bf(s2) | ((unsigned)f2bf(-2.0f * s2 * m) << 16);
            float cp = s2 * m * m;
            #pragma unroll
            for (int off = 32; off > 0; off >>= 1) cp += __shfl_down(cp, off, 64);
            if (lane == 0) red[wv] = cp;
            __syncthreads();
            if (t == 0) c[f] = red[0] + red[1] + red[2] + red[3];
            __syncthreads();
        }
        #pragma unroll
        for (int rr = 0; rr < 4; ++rr) {
            const int i = (bid * 4 + rr) * DIM + t;
            const float v = x[i];
            Ab32[i] = (unsigned)f2bf(v * v) | ((unsigned)f2bf(v) << 16);
        }
    }

    grid.sync();

    // ---- phase 1: GEMM tile (r5 structure) ----
    const int w = t >> 6;
    const int lane = t & 63;
    const int m16 = lane & 15;
    const int q = lane >> 4;
    const int wr = w >> 1, wc = w & 1;

    const int xcd = bid & 7;
    const int j = bid >> 3;
    const int nc = j & 15;
    const int rb = xcd * 4 + (j >> 4);
    const int r0 = rb * BM;
    const int n0 = nc * BN;

    // stage whole 64x512 A tile once (XOR-swizzled slots)
    #pragma unroll
    for (int i = 0; i < 16; ++i) {
        const int s = i * 256 + t;
        const int row = s >> 6;
        const int kcp = s & 63;
        const int kcl = (kcp & 56) | ((kcp & 7) ^ (row & 7));
        gl_lds16(Ab + (r0 + row) * K + kcl * 8, &Alds[s * 8]);
    }

    f32x4 acc[2][2];
    #pragma unroll
    for (int rt = 0; rt < 2; ++rt)
        #pragma unroll
        for (int ct = 0; ct < 2; ++ct) acc[rt][ct] = (f32x4){0.f, 0.f, 0.f, 0.f};

    const ushort* __restrict__ Brow0 = Bb + (n0 + wc * 32 + m16) * K;
    const ushort* __restrict__ Brow1 = Brow0 + 16 * K;

    __syncthreads();    // drain A stage

    #pragma unroll
    for (int ks = 0; ks < K; ks += 32) {
        const int kcq = (ks >> 3) + q;
        short8 av[2], bv[2];
        bv[0] = *(const short8*)&Brow0[ks + q * 8];
        bv[1] = *(const short8*)&Brow1[ks + q * 8];
        #pragma unroll
        for (int jj = 0; jj < 2; ++jj) {
            const int ar = wr * 32 + jj * 16 + m16;
            const int slot = (kcq & 56) | ((kcq & 7) ^ (ar & 7));
            av[jj] = *(const short8*)&Alds[ar * K + slot * 8];
        }
        #pragma unroll
        for (int rt = 0; rt < 2; ++rt)
            #pragma unroll
            for (int ct = 0; ct < 2; ++ct)
                acc[rt][ct] = __builtin_amdgcn_mfma_f32_16x16x32_bf16(
                    av[rt], bv[ct], acc[rt][ct], 0, 0, 0);
    }

    // epilogue: p = exp(g*exp(-dist)) -> REGISTERS; partial sums -> rowPartial
    const float g = 1.0f / (1.0f + __expf(-temp[0]));
    float preg[2][2][4];
    #pragma unroll
    for (int rt = 0; rt < 2; ++rt) {
        float s[4] = {0.f, 0.f, 0.f, 0.f};
        #pragma unroll
        for (int ct = 0; ct < 2; ++ct) {
            const float cn = c[n0 + wc * 32 + ct * 16 + m16];
            #pragma unroll
            for (int i = 0; i < 4; ++i) {
                const float dist2 = acc[rt][ct][i] + cn;
                const float dist = sqrtf(fmaxf(dist2, 0.0f));
                const float p = __expf(g * __expf(-dist));
                preg[rt][ct][i] = p;
                s[i] += p;
            }
        }
        #pragma unroll
        for (int i = 0; i < 4; ++i) {
            #pragma unroll
            for (int mask = 1; mask < 16; mask <<= 1)
                s[i] += __shfl_xor(s[i], mask, 64);
        }
        if (m16 == 0) {
            #pragma unroll
            for (int i = 0; i < 4; ++i) sums[w][rt * 16 + q * 4 + i] = s[i];
        }
    }
    __syncthreads();
    if (t < BM) {
        const int half = t >> 5, lr = t & 31;
        rowPartial[nc * BATCH + r0 + t] =
            sums[half * 2][lr] + sums[half * 2 + 1][lr];
    }

    grid.sync();

    // ---- phase 2: normalize in-register, single out write ----
    if (t < BM) {
        float ss = 0.0f;
        #pragma unroll
        for (int ch = 0; ch < NCHUNK; ++ch) ss += rowPartial[ch * BATCH + r0 + t];
        invRow[t] = 1.0f / ss;
    }
    __syncthreads();
    #pragma unroll
    for (int rt = 0; rt < 2; ++rt)
        #pragma unroll
        for (int ct = 0; ct < 2; ++ct) {
            const int fcol = n0 + wc * 32 + ct * 16 + m16;
            #pragma unroll
            for (int i = 0; i < 4; ++i) {
                const int lrow = wr * 32 + rt * 16 + q * 4 + i;
                out[(r0 + lrow) * NF + fcol] = preg[rt][ct][i] * invRow[lrow];
            }
        }
}

extern "C" void kernel_launch(void* const* d_in, const int* in_sizes, int n_in,
                              void* d_out, int out_size, void* d_ws, size_t ws_size,
                              hipStream_t stream) {
    const float* x     = (const float*)d_in[0];
    const float* mu    = (const float*)d_in[1];
    const float* sigma = (const float*)d_in[2];
    const float* temp  = (const float*)d_in[3];
    float* out = (float*)d_out;

    char* ws = (char*)d_ws;
    ushort* Ab         = (ushort*)ws;
    ushort* Bb         = (ushort*)(ws + WS_B_OFF);
    float*  c          = (float*)(ws + WS_C_OFF);
    float*  rowPartial = (float*)(ws + WS_RP_OFF);

    void* args[] = {(void*)&x, (void*)&mu, (void*)&sigma, (void*)&temp,
                    (void*)&out, (void*)&Ab, (void*)&Bb, (void*)&c,
                    (void*)&rowPartial};
    hipLaunchCooperativeKernel((const void*)k_fused, dim3(GRID), dim3(256),
                               args, 0, stream);
}